// Round 2
// baseline (432.492 us; speedup 1.0000x reference)
//
#include <hip/hip_runtime.h>
#include <hip/hip_bf16.h>

typedef __bf16 bf16_t;
typedef __bf16 bf16x8 __attribute__((ext_vector_type(8)));
typedef __bf16 bf16x4 __attribute__((ext_vector_type(4)));
typedef float  f32x4  __attribute__((ext_vector_type(4)));

#define T_TOK 1024
#define DDIM  1024
#define FDIM  2048
#define NEXP  16
#define MAXR  192   // max tokens handled per expert (cnt ~ 128 +/- 11)

// ---------------- workspace layout (bytes), peak 21.1 MB ----------------
// [0, 64)        : int cnt[NEXP]                (memset each call)
// [1024, +64K)   : int   entry[NEXP][T_TOK]     (value = t*2 + slot)
// [66560, +64K)  : float entry_w[NEXP][T_TOK]
// [132096, +8M)  : OVERLAY: xg[NEXP][MAXR][DDIM] bf16 (gather..ffn1)
//                  then    partial[2][T_TOK][DDIM] f32 (ffn2..add)
// [8520704, +12.6M): bf16 fuse[NEXP][MAXR][FDIM]
#define WS_ENTRY_OFF   1024
#define WS_ENTRYW_OFF  66560
#define WS_XG_OFF      132096
#define WS_PART_OFF    132096
#define WS_FUSE_OFF    8520704

#define GLL16(g, l) __builtin_amdgcn_global_load_lds(                      \
    (const __attribute__((address_space(1))) unsigned int*)(g),            \
    (__attribute__((address_space(3))) unsigned int*)(l), 16, 0, 0)

// pipeline sync helpers (T3/T4: counted vmcnt, loads live across barriers)
#define FENCE()   asm volatile("" ::: "memory")
#define WAITVM(N) asm volatile("s_waitcnt vmcnt(" #N ")" ::: "memory")
#define WAITLG()  asm volatile("s_waitcnt lgkmcnt(0)" ::: "memory")
#define SCHEDB()  __builtin_amdgcn_sched_barrier(0)
#define SBAR()    __builtin_amdgcn_s_barrier()

// ---------------- router: one block (64 thr) per token ----------------
__global__ __launch_bounds__(64) void router_kernel(
    const float* __restrict__ x, const float* __restrict__ rw,
    int* __restrict__ cnt, int* __restrict__ entry, float* __restrict__ entry_w)
{
    const int t = blockIdx.x;
    const int lane = threadIdx.x;   // 0..63
    float acc[NEXP];
#pragma unroll
    for (int e = 0; e < NEXP; ++e) acc[e] = 0.f;
#pragma unroll
    for (int i = 0; i < DDIM / 64; ++i) {
        const int d = lane + i * 64;
        const float xv = x[(size_t)t * DDIM + d];
        const float* r = rw + (size_t)d * NEXP;
#pragma unroll
        for (int e = 0; e < NEXP; ++e) acc[e] += xv * r[e];
    }
#pragma unroll
    for (int e = 0; e < NEXP; ++e) {
        float v = acc[e];
        for (int off = 32; off > 0; off >>= 1) v += __shfl_down(v, off);
        acc[e] = v;
    }
    if (lane == 0) {
        int i0 = -1, i1 = -1;
        float v0 = -1e30f, v1 = -1e30f;
#pragma unroll
        for (int e = 0; e < NEXP; ++e) {
            const float v = acc[e];
            if (v > v0)      { v1 = v0; i1 = i0; v0 = v; i0 = e; }
            else if (v > v1) { v1 = v;  i1 = e; }
        }
        const float e1 = __expf(v1 - v0);
        const float w0 = 1.f / (1.f + e1);
        const float w1 = e1 / (1.f + e1);
        int p = atomicAdd(&cnt[i0], 1);
        entry[i0 * T_TOK + p] = t * 2 + 0;
        entry_w[i0 * T_TOK + p] = w0;
        p = atomicAdd(&cnt[i1], 1);
        entry[i1 * T_TOK + p] = t * 2 + 1;
        entry_w[i1 * T_TOK + p] = w1;
    }
}

// ---------------- gather: x -> expert-local bf16 xg[e][i][d] ----------------
// grid (NEXP, MAXR/4), 256 thr; 4 rows per block (768 blocks: fills the GPU,
// kills the serial 32-row latency chain of the old 96-block version).
__global__ __launch_bounds__(256) void gather_kernel(
    const float* __restrict__ x, const int* __restrict__ cnt,
    const int* __restrict__ entry, bf16_t* __restrict__ xg)
{
    const int e  = blockIdx.x;
    const int i0 = blockIdx.y * 4;
    const int tid = threadIdx.x;
    int n_tok = cnt[e]; if (n_tok > MAXR) n_tok = MAXR;
#pragma unroll
    for (int rr = 0; rr < 4; ++rr) {
        const int i = i0 + rr;
        bf16x4 v4;
        v4[0] = (bf16_t)0.f; v4[1] = (bf16_t)0.f; v4[2] = (bf16_t)0.f; v4[3] = (bf16_t)0.f;
        if (i < n_tok) {
            const int tok = entry[e * T_TOK + i] >> 1;
            const float4 v = *(const float4*)(x + (size_t)tok * DDIM + tid * 4);
            v4[0] = (bf16_t)v.x; v4[1] = (bf16_t)v.y; v4[2] = (bf16_t)v.z; v4[3] = (bf16_t)v.w;
        }
        *(bf16x4*)(xg + ((size_t)e * MAXR + i) * DDIM + tid * 4) = v4;
    }
}

// ---------------- phase 1: gating+up MFMA GEMM + silu-fuse ----------------
// grid (NEXP, FDIM/64), 256 thr. BM=192, BN=64, BK=32.
// Counted-vmcnt pipeline (T3/T4): per iter, per wave issues L_B=16 scalar f32
// loads + G_A=3 GLLs; waits are counted so ~19 VMEM ops stay in flight across
// every barrier (never vmcnt(0) in the loop).
// vmcnt ledger (steady state, at loop head): G_A(t)=3 + L_B(t+1)=16 +
// G_A(t+1)=3 = 22 outstanding -> WAITVM(19) drains exactly G_A(t);
// WAITVM(3) drains L_B(t+1) before the B-pack.
// A-tile k-chunks carry an XOR swizzle (slot = (lane&3)^(row&3)) on the GLOBAL
// source + fragment read; GLL dest stays linear (rule 21). Note: with 64B rows
// both layouts are at the 8-words/bank LDS floor -- swizzle is perf-neutral,
// kept because it is correct and free.
// A-tiles are wave-private (wave GLLs + reads only its own 48 rows) => only Bs
// needs barrier protection; own As reads are drained by lgkmcnt(0) before the
// buffer is re-targeted.
__global__ __launch_bounds__(256, 2) void ffn1_kernel(
    const bf16_t* __restrict__ xg,
    const float* __restrict__ wg, const float* __restrict__ wu,
    const int* __restrict__ cnt, const int* __restrict__ entry,
    bf16_t* __restrict__ fuse)
{
    const int e  = blockIdx.x;
    const int f0 = blockIdx.y * 64;
    int n_tok = cnt[e]; if (n_tok > MAXR) n_tok = MAXR;

    __shared__ __align__(16) bf16_t As[2][MAXR][32];   // 24 KB
    __shared__ __align__(16) bf16_t Bgs[2][64][40];    // 10 KB (pad 8 -> bank-spread)
    __shared__ __align__(16) bf16_t Bus[2][64][40];    // 10 KB
    __shared__ int sem[MAXR];

    const int tid  = threadIdx.x;
    const int wave = tid >> 6;
    const int lane = tid & 63;
    const int r    = lane & 15;
    const int q    = lane >> 4;
    const int arow = lane >> 2;
    const int slot = (lane & 3) ^ (arow & 3);   // k-chunk src swizzle (involution)

    const bf16_t* xg_e = xg + (size_t)e * MAXR * DDIM;
    const float* wg_p = wg + (size_t)e * DDIM * FDIM + (size_t)(wave * 8) * FDIM + f0 + lane;
    const float* wu_p = wu + (size_t)e * DDIM * FDIM + (size_t)(wave * 8) * FDIM + f0 + lane;

    if (tid < MAXR) sem[tid] = (tid < n_tok) ? entry[e * T_TOK + tid] : -1;

    float rg[8], ru[8];
    // ---- prologue: L_B(0)
#pragma unroll
    for (int j = 0; j < 8; ++j) { rg[j] = wg_p[(size_t)j * FDIM]; ru[j] = wu_p[(size_t)j * FDIM]; }
    FENCE();
    // ---- G_A(0) -> As[0]
#pragma unroll
    for (int c = 0; c < 3; ++c) {
        const int rowb = wave * 48 + c * 16;
        const bf16_t* g = xg_e + (size_t)(rowb + arow) * DDIM + slot * 8;
        GLL16(g, &As[0][rowb][0] + lane * 8);
    }
    FENCE();
    WAITVM(3);                       // L_B(0) done (G_A(0)=3 still outstanding)
    {
        bf16x8 pg, pu;
#pragma unroll
        for (int j = 0; j < 8; ++j) { pg[j] = (bf16_t)rg[j]; pu[j] = (bf16_t)ru[j]; }
        *(bf16x8*)&Bgs[0][lane][wave * 8] = pg;
        *(bf16x8*)&Bus[0][lane][wave * 8] = pu;
    }
    // ---- L_B(1)
    wg_p += (size_t)32 * FDIM; wu_p += (size_t)32 * FDIM;
#pragma unroll
    for (int j = 0; j < 8; ++j) { rg[j] = wg_p[(size_t)j * FDIM]; ru[j] = wu_p[(size_t)j * FDIM]; }
    FENCE();
    // ---- G_A(1) -> As[1]
#pragma unroll
    for (int c = 0; c < 3; ++c) {
        const int rowb = wave * 48 + c * 16;
        const bf16_t* g = xg_e + (size_t)(rowb + arow) * DDIM + 32 + slot * 8;
        GLL16(g, &As[1][rowb][0] + lane * 8);
    }
    FENCE();
    WAITLG();                        // Bs[0] pack visible
    SBAR();

    f32x4 accg[3][4], accu[3][4];
#pragma unroll
    for (int a = 0; a < 3; ++a)
#pragma unroll
        for (int b = 0; b < 4; ++b) {
            accg[a][b] = (f32x4){0.f, 0.f, 0.f, 0.f};
            accu[a][b] = (f32x4){0.f, 0.f, 0.f, 0.f};
        }

    for (int t = 0; t < 32; ++t) {
        const int cur = t & 1;
        // R-wait: G_A(t) done. Issued after it: L_B(t+1)=16 + G_A(t+1)=3 = 19.
        if (t == 31) { WAITVM(0); } else { WAITVM(19); }
        SCHEDB();
        bf16x8 af[3], bg[4], bu[4];
#pragma unroll
        for (int mt = 0; mt < 3; ++mt) {
            const int m = wave * 48 + mt * 16 + r;
            af[mt] = *(const bf16x8*)&As[cur][m][(q ^ (r & 3)) * 8];
        }
#pragma unroll
        for (int nt = 0; nt < 4; ++nt) {
            bg[nt] = *(const bf16x8*)&Bgs[cur][nt * 16 + r][q * 8];
            bu[nt] = *(const bf16x8*)&Bus[cur][nt * 16 + r][q * 8];
        }
        if (t < 31) {
            WAITVM(3);               // L_B(t+1) done (G_A(t+1)=3 outstanding)
            bf16x8 pg, pu;
#pragma unroll
            for (int j = 0; j < 8; ++j) { pg[j] = (bf16_t)rg[j]; pu[j] = (bf16_t)ru[j]; }
            *(bf16x8*)&Bgs[cur ^ 1][lane][wave * 8] = pg;
            *(bf16x8*)&Bus[cur ^ 1][lane][wave * 8] = pu;
        }
        WAITLG();                    // frags in regs; pack visible; As[cur] reads done
        SCHEDB();
        if (t < 30) {
            // prefetch t+2: L_B then G_A -> As[cur] (safe: own As[cur] reads drained)
            wg_p += (size_t)32 * FDIM; wu_p += (size_t)32 * FDIM;
#pragma unroll
            for (int j = 0; j < 8; ++j) { rg[j] = wg_p[(size_t)j * FDIM]; ru[j] = wu_p[(size_t)j * FDIM]; }
            FENCE();
            const int kk = (t + 2) * 32;
#pragma unroll
            for (int c = 0; c < 3; ++c) {
                const int rowb = wave * 48 + c * 16;
                const bf16_t* g = xg_e + (size_t)(rowb + arow) * DDIM + kk + slot * 8;
                GLL16(g, &As[cur][rowb][0] + lane * 8);
            }
            FENCE();
        }
        __builtin_amdgcn_s_setprio(1);
#pragma unroll
        for (int mt = 0; mt < 3; ++mt)
#pragma unroll
            for (int nt = 0; nt < 4; ++nt) {
                accg[mt][nt] = __builtin_amdgcn_mfma_f32_16x16x32_bf16(af[mt], bg[nt], accg[mt][nt], 0, 0, 0);
                accu[mt][nt] = __builtin_amdgcn_mfma_f32_16x16x32_bf16(af[mt], bu[nt], accu[mt][nt], 0, 0, 0);
            }
        __builtin_amdgcn_s_setprio(0);
        SBAR();
    }

    // epilogue: silu(g)*u -> fuse[e][m][f] (bf16), zeros for padded rows
    bf16_t* fuse_e = fuse + (size_t)e * MAXR * FDIM + f0;
#pragma unroll
    for (int mt = 0; mt < 3; ++mt) {
#pragma unroll
        for (int j = 0; j < 4; ++j) {
            const int m = wave * 48 + mt * 16 + q * 4 + j;
            const bool valid = sem[m] >= 0;
            bf16_t* dst = fuse_e + (size_t)m * FDIM;
#pragma unroll
            for (int nt = 0; nt < 4; ++nt) {
                const float g = accg[mt][nt][j];
                const float u = accu[mt][nt][j];
                const float h = valid ? (g / (1.f + __expf(-g))) * u : 0.f;
                dst[nt * 16 + r] = (bf16_t)h;
            }
        }
    }
}

// ---------------- phase 2: down MFMA GEMM, weighted -> partial ----------------
// grid (NEXP, DDIM/32), 256 thr. BM=192, BN=32, BK=64.
// Same counted-vmcnt pipeline: L_B=8, G_A=6 per iter.
// Ledger: loop head outstanding = 6+8+6 = 20 -> WAITVM(14) drains G_A(t);
// WAITVM(6) drains L_B(t+1).
__global__ __launch_bounds__(256, 2) void ffn2_kernel(
    const bf16_t* __restrict__ fuse, const float* __restrict__ wd,
    const int* __restrict__ cnt, const int* __restrict__ entry,
    const float* __restrict__ entry_w, float* __restrict__ partial)
{
    const int e  = blockIdx.x;
    const int d0 = blockIdx.y * 32;
    int n_tok = cnt[e]; if (n_tok > MAXR) n_tok = MAXR;

    __shared__ __align__(16) bf16_t As[2][2][MAXR][32];  // [buf][khalf][m][k] 48 KB
    __shared__ __align__(16) bf16_t Bs[2][32][72];       // 9 KB (pad 8)
    __shared__ int   sem[MAXR];
    __shared__ float sw[MAXR];

    const int tid  = threadIdx.x;
    const int wave = tid >> 6;
    const int lane = tid & 63;
    const int r    = lane & 15;
    const int q    = lane >> 4;
    const int arow = lane >> 2;
    const int slot = (lane & 3) ^ (arow & 3);

    const bf16_t* fu_e = fuse + (size_t)e * MAXR * FDIM;
    const int bn = tid & 31;
    const int k8 = (tid >> 5) * 8;
    const float* wd_p = wd + (size_t)e * FDIM * DDIM + (size_t)k8 * DDIM + d0 + bn;

    if (tid < MAXR) {
        sem[tid] = (tid < n_tok) ? entry[e * T_TOK + tid] : -1;
        sw[tid]  = (tid < n_tok) ? entry_w[e * T_TOK + tid] : 0.f;
    }

    float rb[8];
    // ---- prologue: L_B(0)
#pragma unroll
    for (int j = 0; j < 8; ++j) rb[j] = wd_p[(size_t)j * DDIM];
    FENCE();
    // ---- G_A(0) -> As[0]
#pragma unroll
    for (int ks = 0; ks < 2; ++ks)
#pragma unroll
        for (int c = 0; c < 3; ++c) {
            const int rowb = wave * 48 + c * 16;
            const bf16_t* g = fu_e + (size_t)(rowb + arow) * FDIM + ks * 32 + slot * 8;
            GLL16(g, &As[0][ks][rowb][0] + lane * 8);
        }
    FENCE();
    WAITVM(6);                       // L_B(0) done (G_A(0)=6 outstanding)
    {
        bf16x8 pb;
#pragma unroll
        for (int j = 0; j < 8; ++j) pb[j] = (bf16_t)rb[j];
        *(bf16x8*)&Bs[0][bn][k8] = pb;
    }
    // ---- L_B(1)
    wd_p += (size_t)64 * DDIM;
#pragma unroll
    for (int j = 0; j < 8; ++j) rb[j] = wd_p[(size_t)j * DDIM];
    FENCE();
    // ---- G_A(1) -> As[1]
#pragma unroll
    for (int ks = 0; ks < 2; ++ks)
#pragma unroll
        for (int c = 0; c < 3; ++c) {
            const int rowb = wave * 48 + c * 16;
            const bf16_t* g = fu_e + (size_t)(rowb + arow) * FDIM + 64 + ks * 32 + slot * 8;
            GLL16(g, &As[1][ks][rowb][0] + lane * 8);
        }
    FENCE();
    WAITLG();
    SBAR();

    f32x4 acc[3][2];
#pragma unroll
    for (int a = 0; a < 3; ++a)
#pragma unroll
        for (int b = 0; b < 2; ++b) acc[a][b] = (f32x4){0.f, 0.f, 0.f, 0.f};

    for (int t = 0; t < 32; ++t) {
        const int cur = t & 1;
        // G_A(t) done: issued after = L_B(t+1)=8 + G_A(t+1)=6 = 14.
        if (t == 31) { WAITVM(0); } else { WAITVM(14); }
        SCHEDB();
        bf16x8 af2[2][3], bb2[2][2];
#pragma unroll
        for (int ks = 0; ks < 2; ++ks) {
#pragma unroll
            for (int mt = 0; mt < 3; ++mt) {
                const int m = wave * 48 + mt * 16 + r;
                af2[ks][mt] = *(const bf16x8*)&As[cur][ks][m][(q ^ (r & 3)) * 8];
            }
#pragma unroll
            for (int nt = 0; nt < 2; ++nt)
                bb2[ks][nt] = *(const bf16x8*)&Bs[cur][nt * 16 + r][ks * 32 + q * 8];
        }
        if (t < 31) {
            WAITVM(6);               // L_B(t+1) done (G_A(t+1)=6 outstanding)
            bf16x8 pb;
#pragma unroll
            for (int j = 0; j < 8; ++j) pb[j] = (bf16_t)rb[j];
            *(bf16x8*)&Bs[cur ^ 1][bn][k8] = pb;
        }
        WAITLG();
        SCHEDB();
        if (t < 30) {
            wd_p += (size_t)64 * DDIM;
#pragma unroll
            for (int j = 0; j < 8; ++j) rb[j] = wd_p[(size_t)j * DDIM];
            FENCE();
            const int kk = (t + 2) * 64;
#pragma unroll
            for (int ks = 0; ks < 2; ++ks)
#pragma unroll
                for (int c = 0; c < 3; ++c) {
                    const int rowb = wave * 48 + c * 16;
                    const bf16_t* g = fu_e + (size_t)(rowb + arow) * FDIM + kk + ks * 32 + slot * 8;
                    GLL16(g, &As[cur][ks][rowb][0] + lane * 8);
                }
            FENCE();
        }
        __builtin_amdgcn_s_setprio(1);
#pragma unroll
        for (int ks = 0; ks < 2; ++ks)
#pragma unroll
            for (int mt = 0; mt < 3; ++mt)
#pragma unroll
                for (int nt = 0; nt < 2; ++nt)
                    acc[mt][nt] = __builtin_amdgcn_mfma_f32_16x16x32_bf16(af2[ks][mt], bb2[ks][nt], acc[mt][nt], 0, 0, 0);
        __builtin_amdgcn_s_setprio(0);
        SBAR();
    }

#pragma unroll
    for (int mt = 0; mt < 3; ++mt) {
#pragma unroll
        for (int j = 0; j < 4; ++j) {
            const int m = wave * 48 + mt * 16 + q * 4 + j;
            const int em = sem[m];
            if (em < 0) continue;
            const int t = em >> 1;
            const int sl = em & 1;
            const float w = sw[m];
            float* dst = partial + ((size_t)sl * T_TOK + t) * DDIM + d0;
#pragma unroll
            for (int nt = 0; nt < 2; ++nt)
                dst[nt * 16 + r] = acc[mt][nt][j] * w;
        }
    }
}

// ---------------- phase 3: out = partial[0] + partial[1] ----------------
__global__ __launch_bounds__(256) void add_kernel(
    const float* __restrict__ partial, float* __restrict__ out)
{
    const int i = blockIdx.x * blockDim.x + threadIdx.x;   // over T*D/4
    const float4 a = ((const float4*)partial)[i];
    const float4 b = ((const float4*)(partial + (size_t)T_TOK * DDIM))[i];
    float4 o;
    o.x = a.x + b.x; o.y = a.y + b.y; o.z = a.z + b.z; o.w = a.w + b.w;
    ((float4*)out)[i] = o;
}

extern "C" void kernel_launch(void* const* d_in, const int* in_sizes, int n_in,
                              void* d_out, int out_size, void* d_ws, size_t ws_size,
                              hipStream_t stream) {
    const float* x  = (const float*)d_in[0];
    const float* rw = (const float*)d_in[1];
    const float* wg = (const float*)d_in[2];
    const float* wu = (const float*)d_in[3];
    const float* wd = (const float*)d_in[4];
    float* out = (float*)d_out;

    char* ws = (char*)d_ws;
    int*    cnt     = (int*)ws;
    int*    entry   = (int*)(ws + WS_ENTRY_OFF);
    float*  entry_w = (float*)(ws + WS_ENTRYW_OFF);
    bf16_t* xg      = (bf16_t*)(ws + WS_XG_OFF);
    float*  partial = (float*)(ws + WS_PART_OFF);   // overlays xg (disjoint lifetime)
    bf16_t* fuse    = (bf16_t*)(ws + WS_FUSE_OFF);

    hipMemsetAsync(cnt, 0, 64, stream);

    router_kernel<<<T_TOK, 64, 0, stream>>>(x, rw, cnt, entry, entry_w);

    gather_kernel<<<dim3(NEXP, MAXR / 4), 256, 0, stream>>>(x, cnt, entry, xg);

    ffn1_kernel<<<dim3(NEXP, FDIM / 64), 256, 0, stream>>>(
        xg, wg, wu, cnt, entry, fuse);

    ffn2_kernel<<<dim3(NEXP, DDIM / 32), 256, 0, stream>>>(
        fuse, wd, cnt, entry, entry_w, partial);

    add_kernel<<<(T_TOK * DDIM / 4) / 256, 256, 0, stream>>>(partial, out);
}